// Round 1
// baseline (7859.663 us; speedup 1.0000x reference)
//
#include <hip/hip_runtime.h>
#include <math.h>

#define BB 16
#define SS 256
#define DD 41
#define LL (SS*DD)      // 10496
#define LAT 128
#define NH 4
#define NL 3
#define KSPLIT 8
#define CHUNK ((LL + KSPLIT - 1) / KSPLIT)   // 1312
#define RSQ 0.08838834764831845f             // 1/sqrt(128)

// ---------------- stable compaction: valid first, original order ----------------
__global__ __launch_bounds__(256)
void k_compact(const float* __restrict__ time_x, const float* __restrict__ value_x,
               const int* __restrict__ mask_x,
               float* __restrict__ compT, float* __restrict__ compU,
               int* __restrict__ compC, int* __restrict__ nvalid)
{
    int b = blockIdx.x, tid = threadIdx.x;
    __shared__ int sdata[256];
    __shared__ int s_base;
    if (tid == 0) s_base = 0;
    __syncthreads();
    for (int j0 = 0; j0 < LL; j0 += 256) {
        int j = j0 + tid;
        int m = (j < LL) ? mask_x[b * LL + j] : 0;
        sdata[tid] = m;
        __syncthreads();
        for (int off = 1; off < 256; off <<= 1) {
            int v = (tid >= off) ? sdata[tid - off] : 0;
            __syncthreads();
            sdata[tid] += v;
            __syncthreads();
        }
        int incl = sdata[tid];
        int base = s_base;
        if (m && j < LL) {
            int pos = base + incl - m;
            compT[b * LL + pos] = time_x[b * SS + j / DD];
            compU[b * LL + pos] = value_x[b * LL + j];
            compC[b * LL + pos] = j % DD;
        }
        __syncthreads();
        if (tid == 255) s_base = base + incl;
        __syncthreads();
    }
    if (tid == 0) nvalid[b] = s_base;
}

// ---------------- Z init: Z = relu(Wi[c] + t*Wi[41] + u*Wi[42] + bi), mk ----------------
__global__ __launch_bounds__(128)
void k_init(const float* __restrict__ Wi, const float* __restrict__ bi,
            const float* __restrict__ compT, const float* __restrict__ compU,
            const int* __restrict__ compC, const int* __restrict__ nvalid,
            float* __restrict__ out)
{
    int b = blockIdx.y, p = blockIdx.x, k = threadIdx.x;
    float* Z = out;
    float* MK = out + (size_t)BB * LL * LAT;
    int nv = nvalid[b];
    size_t zi = ((size_t)b * LL + p) * LAT + k;
    if (p < nv) {
        int c = compC[b * LL + p];
        float t = compT[b * LL + p], u = compU[b * LL + p];
        float v = Wi[c * LAT + k] + t * Wi[41 * LAT + k] + u * Wi[42 * LAT + k] + bi[k];
        Z[zi] = fmaxf(v, 0.f);
        if (k == 0) MK[b * LL + p] = 1.f;
    } else {
        Z[zi] = 0.f;
        if (k == 0) MK[b * LL + p] = 0.f;
    }
}

// ---------------- Qh0 = I_l @ Wq0 + bq0  (batch-independent) ----------------
__global__ __launch_bounds__(128)
void k_qh0(const float* __restrict__ Il, const float* __restrict__ W,
           const float* __restrict__ bias, float* __restrict__ Qh0)
{
    int q = blockIdx.x, k = threadIdx.x;
    __shared__ float row[128];
    row[k] = Il[q * 128 + k];
    __syncthreads();
    float acc = bias[k];
    for (int i = 0; i < 128; ++i) acc += row[i] * W[i * 128 + k];
    Qh0[q * 128 + k] = acc;
}

// ---------------- MAB0 flash attention (induced -> data), split over keys ----------------
__global__ __launch_bounds__(256)
void k_flash0(const float* __restrict__ Z, const float* __restrict__ Qh0,
              const float* __restrict__ Wk0, const float* __restrict__ bk0,
              const float* __restrict__ Wv0, const float* __restrict__ bv0,
              const int* __restrict__ nvalid, float* __restrict__ part)
{
    const int chunk = blockIdx.x;
    const int h = blockIdx.y;
    const int b = blockIdx.z;
    const int tid = threadIdx.x;

    __shared__ float sWk[128 * 32];     // [i][d]
    __shared__ float sWv[128 * 32];
    __shared__ float sQ[128 * 32];      // [q][d]
    __shared__ float sZ[32 * 128];      // [kk][i]
    __shared__ float sKT[32 * 33];      // [d][kk] stride 33
    __shared__ float sV[32 * 32];       // [kk][d]
    __shared__ float sS[128 * 33];      // [q][kk] stride 33
    __shared__ float sAcc[128 * 32];    // [q][d]
    __shared__ float sM[128], sL[128], sScale[128];
    __shared__ float sBk[32], sBv[32];

    for (int j = 0; j < 16; ++j) {
        int e = j * 256 + tid;
        int row = e >> 5, d = e & 31;
        sWk[e] = Wk0[row * 128 + h * 32 + d];
        sWv[e] = Wv0[row * 128 + h * 32 + d];
        sQ[e]  = Qh0[row * 128 + h * 32 + d];
        sAcc[e] = 0.f;
    }
    if (tid < 32) { sBk[tid] = bk0[h * 32 + tid]; sBv[tid] = bv0[h * 32 + tid]; }
    if (tid < 128) { sM[tid] = -1e30f; sL[tid] = 0.f; }
    __syncthreads();

    int nv = nvalid[b];
    int c0 = chunk * CHUNK;
    int c1 = min(c0 + CHUNK, nv);

    for (int kt = c0; kt < c1; kt += 32) {
        int nk = min(32, c1 - kt);
        for (int j = 0; j < 16; ++j) {
            int e = j * 256 + tid;
            int kk = e >> 7, i = e & 127;
            sZ[e] = (kk < nk) ? Z[((size_t)b * LL + kt + kk) * LAT + i] : 0.f;
        }
        __syncthreads();
        // project K,V for this tile (head slice)
        for (int j = 0; j < 4; ++j) {
            int e = j * 256 + tid;         // 0..1023
            int kk = e >> 5, d = e & 31;
            float ak = sBk[d], av = sBv[d];
            const float* zr = &sZ[kk * 128];
            for (int i = 0; i < 128; ++i) {
                float z = zr[i];
                ak += z * sWk[i * 32 + d];
                av += z * sWv[i * 32 + d];
            }
            sKT[d * 33 + kk] = ak;
            sV[kk * 32 + d]  = av;
        }
        __syncthreads();
        // scores [q][kk]
        for (int j = 0; j < 16; ++j) {
            int e = j * 256 + tid;
            int kk = e & 31, q = e >> 5;
            float acc = 0.f;
            for (int d = 0; d < 32; ++d)
                acc += sQ[q * 32 + d] * sKT[d * 33 + kk];
            sS[q * 33 + kk] = (kk < nk) ? acc * RSQ : -1e30f;
        }
        __syncthreads();
        // online softmax per q
        if (tid < 128) {
            int q = tid;
            float m = sM[q];
            float mt = -1e30f;
            for (int kk = 0; kk < 32; ++kk) mt = fmaxf(mt, sS[q * 33 + kk]);
            float mn = fmaxf(m, mt);
            float sc = __expf(m - mn);
            float l = sL[q] * sc;
            for (int kk = 0; kk < 32; ++kk) {
                float p = __expf(sS[q * 33 + kk] - mn);
                sS[q * 33 + kk] = p;
                l += p;
            }
            sM[q] = mn; sL[q] = l; sScale[q] = sc;
        }
        __syncthreads();
        // acc update
        for (int j = 0; j < 16; ++j) {
            int e = j * 256 + tid;
            int d = e & 31, q = e >> 5;
            float a = sAcc[q * 32 + d] * sScale[q];
            for (int kk = 0; kk < 32; ++kk)
                a += sS[q * 33 + kk] * sV[kk * 32 + d];
            sAcc[q * 32 + d] = a;
        }
        __syncthreads();
    }

    size_t base = (((size_t)b * NH + h) * KSPLIT + chunk) * 128 * 34;
    if (tid < 128) {
        part[base + (size_t)tid * 34 + 0] = sM[tid];
        part[base + (size_t)tid * 34 + 1] = sL[tid];
    }
    for (int j = 0; j < 16; ++j) {
        int e = j * 256 + tid;
        int d = e & 31, q = e >> 5;
        part[base + (size_t)q * 34 + 2 + d] = sAcc[q * 32 + d];
    }
}

// ---------------- merge MAB0 partials -> O0 = Qh0 + attn ----------------
__global__ __launch_bounds__(128)
void k_merge0(const float* __restrict__ part, const float* __restrict__ Qh0,
              float* __restrict__ O0)
{
    int q = threadIdx.x;
    int h = blockIdx.x, b = blockIdx.y;
    size_t pb = (((size_t)b * NH + h) * KSPLIT) * 128 * 34;
    float M = -1e30f;
    for (int c = 0; c < KSPLIT; ++c)
        M = fmaxf(M, part[pb + ((size_t)c * 128 + q) * 34 + 0]);
    float Lsum = 0.f;
    float acc[32];
    for (int d = 0; d < 32; ++d) acc[d] = 0.f;
    for (int c = 0; c < KSPLIT; ++c) {
        const float* pr = &part[pb + ((size_t)c * 128 + q) * 34];
        float sc = __expf(pr[0] - M);
        Lsum += sc * pr[1];
        for (int d = 0; d < 32; ++d) acc[d] += sc * pr[2 + d];
    }
    float inv = 1.f / Lsum;
    for (int d = 0; d < 32; ++d)
        O0[((size_t)b * 128 + q) * 128 + h * 32 + d] =
            Qh0[q * 128 + h * 32 + d] + acc[d] * inv;
}

// ---------------- Y = X + relu(X @ W + b)  (rows = B*128) ----------------
__global__ __launch_bounds__(128)
void k_mlp_res(const float* __restrict__ X, const float* __restrict__ W,
               const float* __restrict__ bias, float* __restrict__ Y)
{
    int row = blockIdx.y * gridDim.x + blockIdx.x;
    int k = threadIdx.x;
    __shared__ float sx[128];
    sx[k] = X[(size_t)row * 128 + k];
    __syncthreads();
    float acc = bias[k];
    for (int i = 0; i < 128; ++i) acc += sx[i] * W[i * 128 + k];
    Y[(size_t)row * 128 + k] = sx[k] + fmaxf(acc, 0.f);
}

// ---------------- Kh1/Vh1 = H @ Wk1 + bk1 / H @ Wv1 + bv1 ----------------
__global__ __launch_bounds__(128)
void k_kv1(const float* __restrict__ H, const float* __restrict__ Wk,
           const float* __restrict__ bk, const float* __restrict__ Wv,
           const float* __restrict__ bv, float* __restrict__ Kh1,
           float* __restrict__ Vh1)
{
    int row = blockIdx.y * gridDim.x + blockIdx.x;
    int k = threadIdx.x;
    __shared__ float sx[128];
    sx[k] = H[(size_t)row * 128 + k];
    __syncthreads();
    float ak = bk[k], av = bv[k];
    for (int i = 0; i < 128; ++i) {
        float x = sx[i];
        ak += x * Wk[i * 128 + k];
        av += x * Wv[i * 128 + k];
    }
    Kh1[(size_t)row * 128 + k] = ak;
    Vh1[(size_t)row * 128 + k] = av;
}

// ---------------- MAB1 fused (data -> induced), 32 rows per block ----------------
__global__ __launch_bounds__(256)
void k_mab1(float* __restrict__ Z, const float* __restrict__ Kh1,
            const float* __restrict__ Vh1,
            const float* __restrict__ Wq, const float* __restrict__ bq,
            const float* __restrict__ Wo, const float* __restrict__ bo,
            const int* __restrict__ nvalid)
{
    int b = blockIdx.y;
    int p0 = blockIdx.x * 32;
    int nv = nvalid[b];
    if (p0 >= nv) return;
    int nr = min(32, nv - p0);
    int tid = threadIdx.x;

    __shared__ float sZ[32 * 128];
    __shared__ float sQ[32 * 128];
    __shared__ float sO[32 * 128];
    __shared__ float sKT[32 * 129];   // [d][kk] stride 129
    __shared__ float sVT[32 * 129];
    __shared__ float sS[32 * 129];    // [r][kk] stride 129 (also reused as GEMM acc)
    __shared__ float sW[32 * 128];    // weight tile staging
    __shared__ float sIr[32];

    for (int j = 0; j < 16; ++j) {
        int e = j * 256 + tid;
        int r = e >> 7, i = e & 127;
        sZ[e] = (r < nr) ? Z[((size_t)b * LL + p0 + r) * LAT + i] : 0.f;
    }
    for (int j = 0; j < 16; ++j) {
        int e = j * 256 + tid;
        int k = e & 127;
        sQ[e] = bq[k];
        sO[e] = 0.f;
    }
    // Qh1 = Z @ Wq + bq, streaming W tiles through LDS
    for (int i0 = 0; i0 < 128; i0 += 32) {
        __syncthreads();
        for (int j = 0; j < 16; ++j) {
            int e = j * 256 + tid;
            int ii = e >> 7, k = e & 127;
            sW[e] = Wq[(i0 + ii) * 128 + k];
        }
        __syncthreads();
        for (int j = 0; j < 16; ++j) {
            int e = j * 256 + tid;
            int r = e >> 7, k = e & 127;
            float a = sQ[e];
            for (int ii = 0; ii < 32; ++ii)
                a += sZ[r * 128 + i0 + ii] * sW[ii * 128 + k];
            sQ[e] = a;
        }
    }
    // attention over 128 induced keys, per head
    for (int h = 0; h < NH; ++h) {
        __syncthreads();
        for (int j = 0; j < 16; ++j) {
            int e = j * 256 + tid;
            int kk = e >> 5, d = e & 31;
            sKT[d * 129 + kk] = Kh1[((size_t)b * 128 + kk) * 128 + h * 32 + d];
            sVT[d * 129 + kk] = Vh1[((size_t)b * 128 + kk) * 128 + h * 32 + d];
        }
        __syncthreads();
        for (int j = 0; j < 16; ++j) {
            int e = j * 256 + tid;
            int kk = e & 127, r = e >> 7;
            float a = 0.f;
            for (int d = 0; d < 32; ++d)
                a += sQ[r * 128 + h * 32 + d] * sKT[d * 129 + kk];
            sS[r * 129 + kk] = a * RSQ;
        }
        __syncthreads();
        if (tid < 32) {
            int r = tid;
            float m = -1e30f;
            for (int kk = 0; kk < 128; ++kk) m = fmaxf(m, sS[r * 129 + kk]);
            float l = 0.f;
            for (int kk = 0; kk < 128; ++kk) {
                float p = __expf(sS[r * 129 + kk] - m);
                sS[r * 129 + kk] = p;
                l += p;
            }
            sIr[r] = 1.f / l;
        }
        __syncthreads();
        for (int j = 0; j < 4; ++j) {
            int e = j * 256 + tid;
            int d = e & 31, r = e >> 5;
            float a = 0.f;
            for (int kk = 0; kk < 128; ++kk)
                a += sS[r * 129 + kk] * sVT[d * 129 + kk];
            sO[r * 128 + h * 32 + d] = a * sIr[r];
        }
    }
    __syncthreads();
    // O = Qh + attn
    for (int j = 0; j < 16; ++j) {
        int e = j * 256 + tid;
        sO[e] += sQ[e];
    }
    // Znew = O + relu(O @ Wo + bo); Z += Znew
    for (int j = 0; j < 16; ++j) {
        int e = j * 256 + tid;
        int r = e >> 7, k = e & 127;
        sS[r * 129 + k] = bo[k];
    }
    for (int i0 = 0; i0 < 128; i0 += 32) {
        __syncthreads();
        for (int j = 0; j < 16; ++j) {
            int e = j * 256 + tid;
            int ii = e >> 7, k = e & 127;
            sW[e] = Wo[(i0 + ii) * 128 + k];
        }
        __syncthreads();
        for (int j = 0; j < 16; ++j) {
            int e = j * 256 + tid;
            int r = e >> 7, k = e & 127;
            float a = sS[r * 129 + k];
            for (int ii = 0; ii < 32; ++ii)
                a += sO[r * 128 + i0 + ii] * sW[ii * 128 + k];
            sS[r * 129 + k] = a;
        }
    }
    __syncthreads();
    for (int j = 0; j < 16; ++j) {
        int e = j * 256 + tid;
        int r = e >> 7, k = e & 127;
        if (r < nr)
            Z[((size_t)b * LL + p0 + r) * LAT + k] =
                sZ[e] + sO[e] + fmaxf(sS[r * 129 + k], 0.f);
    }
}

extern "C" void kernel_launch(void* const* d_in, const int* in_sizes, int n_in,
                              void* d_out, int out_size, void* d_ws, size_t ws_size,
                              hipStream_t stream)
{
    const float* time_x  = (const float*)d_in[0];
    const float* value_x = (const float*)d_in[1];
    const int*   mask_x  = (const int*)d_in[2];
    const float* Wi = (const float*)d_in[3];
    const float* bi = (const float*)d_in[4];
    const float* I  = (const float*)d_in[5];
    const float* Wq = (const float*)d_in[6];
    const float* bq = (const float*)d_in[7];
    const float* Wk = (const float*)d_in[8];
    const float* bk = (const float*)d_in[9];
    const float* Wv = (const float*)d_in[10];
    const float* bv = (const float*)d_in[11];
    const float* Wo = (const float*)d_in[12];
    const float* bo = (const float*)d_in[13];
    float* out = (float*)d_out;

    const size_t BL = (size_t)BB * LL;
    float* ws     = (float*)d_ws;
    float* compT  = ws;
    float* compU  = ws + BL;
    int*   compC  = (int*)(ws + 2 * BL);
    int*   nvalid = (int*)(ws + 3 * BL);
    float* Qh0    = ws + 3 * BL + 64;
    float* O0     = Qh0 + 16384;
    float* H      = O0 + (size_t)BB * 16384;
    float* Kh1    = H + (size_t)BB * 16384;
    float* Vh1    = Kh1 + (size_t)BB * 16384;
    float* part   = Vh1 + (size_t)BB * 16384;   // B*NH*KSPLIT*128*34 floats

    k_compact<<<BB, 256, 0, stream>>>(time_x, value_x, mask_x, compT, compU, compC, nvalid);
    k_init<<<dim3(LL, BB), 128, 0, stream>>>(Wi, bi, compT, compU, compC, nvalid, out);

    for (int l = 0; l < NL; ++l) {
        const float* Wq0 = Wq + (size_t)(l * 2 + 0) * 16384;
        const float* Wk0 = Wk + (size_t)(l * 2 + 0) * 16384;
        const float* Wv0 = Wv + (size_t)(l * 2 + 0) * 16384;
        const float* Wo0 = Wo + (size_t)(l * 2 + 0) * 16384;
        const float* Wq1 = Wq + (size_t)(l * 2 + 1) * 16384;
        const float* Wk1 = Wk + (size_t)(l * 2 + 1) * 16384;
        const float* Wv1 = Wv + (size_t)(l * 2 + 1) * 16384;
        const float* Wo1 = Wo + (size_t)(l * 2 + 1) * 16384;
        const float* bq0 = bq + (l * 2 + 0) * 128;
        const float* bk0 = bk + (l * 2 + 0) * 128;
        const float* bv0 = bv + (l * 2 + 0) * 128;
        const float* bo0 = bo + (l * 2 + 0) * 128;
        const float* bq1 = bq + (l * 2 + 1) * 128;
        const float* bk1 = bk + (l * 2 + 1) * 128;
        const float* bv1 = bv + (l * 2 + 1) * 128;
        const float* bo1 = bo + (l * 2 + 1) * 128;
        const float* Il  = I + (size_t)l * 16384;

        k_qh0<<<128, 128, 0, stream>>>(Il, Wq0, bq0, Qh0);
        k_flash0<<<dim3(KSPLIT, NH, BB), 256, 0, stream>>>(out, Qh0, Wk0, bk0, Wv0, bv0,
                                                           nvalid, part);
        k_merge0<<<dim3(NH, BB), 128, 0, stream>>>(part, Qh0, O0);
        k_mlp_res<<<dim3(128, BB), 128, 0, stream>>>(O0, Wo0, bo0, H);
        k_kv1<<<dim3(128, BB), 128, 0, stream>>>(H, Wk1, bk1, Wv1, bv1, Kh1, Vh1);
        k_mab1<<<dim3((LL + 31) / 32, BB), 256, 0, stream>>>(out, Kh1, Vh1,
                                                             Wq1, bq1, Wo1, bo1, nvalid);
    }
}

// Round 2
// 643.612 us; speedup vs baseline: 12.2118x; 12.2118x over previous
//
#include <hip/hip_runtime.h>
#include <math.h>

#define BB 16
#define SS 256
#define DD 41
#define LL (SS*DD)      // 10496
#define LAT 128
#define NH 4
#define NL 3
#define KS 16           // key-split for MAB0
#define RSQ 0.08838834764831845f             // 1/sqrt(128)

typedef short bf16x8 __attribute__((ext_vector_type(8)));
typedef float f32x4 __attribute__((ext_vector_type(4)));
#define MFMA __builtin_amdgcn_mfma_f32_16x16x32_bf16

__device__ __forceinline__ unsigned short f2b(float f) {
    unsigned u = __builtin_bit_cast(unsigned, f);
    unsigned r = (u + 0x7FFFu + ((u >> 16) & 1u)) >> 16;
    return (unsigned short)r;
}
__device__ __forceinline__ float b2f(unsigned short h) {
    unsigned u = ((unsigned)h) << 16;
    return __builtin_bit_cast(float, u);
}

// ---------------- stable compaction (ballot/popcount scan) ----------------
__global__ __launch_bounds__(256)
void k_compact(const float* __restrict__ time_x, const float* __restrict__ value_x,
               const int* __restrict__ mask_x,
               float* __restrict__ compT, float* __restrict__ compU,
               int* __restrict__ compC, int* __restrict__ nvalid)
{
    int b = blockIdx.x, tid = threadIdx.x;
    int lane = tid & 63, w = tid >> 6;
    __shared__ int sW[4];
    __shared__ int s_base;
    if (tid == 0) s_base = 0;
    __syncthreads();
    for (int j0 = 0; j0 < LL; j0 += 256) {
        int j = j0 + tid;
        int m = mask_x[b * LL + j];
        unsigned long long bal = __ballot(m != 0);
        int pre = __popcll(bal & ((1ull << lane) - 1ull));
        if (lane == 0) sW[w] = __popcll(bal);
        __syncthreads();
        int woff = 0;
        for (int i = 0; i < w; ++i) woff += sW[i];
        int tot = sW[0] + sW[1] + sW[2] + sW[3];
        if (m) {
            int pos = s_base + woff + pre;
            compT[b * LL + pos] = time_x[b * SS + j / DD];
            compU[b * LL + pos] = value_x[b * LL + j];
            compC[b * LL + pos] = j % DD;
        }
        __syncthreads();
        if (tid == 0) s_base += tot;
        __syncthreads();
    }
    if (tid == 0) nvalid[b] = s_base;
}

// ---------------- Z init ----------------
__global__ __launch_bounds__(256)
void k_init(const float* __restrict__ Wi, const float* __restrict__ bi,
            const float* __restrict__ compT, const float* __restrict__ compU,
            const int* __restrict__ compC, const int* __restrict__ nvalid,
            float* __restrict__ out)
{
    int b = blockIdx.y, p0 = blockIdx.x * 8, tid = threadIdx.x;
    float* Z = out;
    float* MK = out + (size_t)BB * LL * LAT;
    int nv = nvalid[b];
    for (int s = 0; s < 4; ++s) {
        int e = s * 256 + tid;
        int r = e >> 7, k = e & 127;
        int p = p0 + r;
        size_t zi = ((size_t)b * LL + p) * LAT + k;
        if (p < nv) {
            int c = compC[b * LL + p];
            float t = compT[b * LL + p], u = compU[b * LL + p];
            float v = Wi[c * LAT + k] + t * Wi[41 * LAT + k] + u * Wi[42 * LAT + k] + bi[k];
            Z[zi] = fmaxf(v, 0.f);
        } else {
            Z[zi] = 0.f;
        }
        if (k == 0) MK[b * LL + p] = (p < nv) ? 1.f : 0.f;
    }
}

// ---------------- per-layer prep: Qh0 (f32+bf16), transposed bf16 weights ----------------
__global__ __launch_bounds__(256)
void k_prep(const float* __restrict__ Il, const float* __restrict__ Wq0,
            const float* __restrict__ bq0,
            const float* __restrict__ Wk0, const float* __restrict__ Wv0,
            const float* __restrict__ Wq1, const float* __restrict__ Wo1,
            float* __restrict__ Qh0f, unsigned short* __restrict__ Qh0b,
            unsigned short* __restrict__ WkT, unsigned short* __restrict__ WvT,
            unsigned short* __restrict__ WqT, unsigned short* __restrict__ WoT)
{
    __shared__ float srow[128];
    int blk = blockIdx.x, tid = threadIdx.x;
    if (blk < 128) {
        if (tid < 128) srow[tid] = Il[blk * 128 + tid];
        __syncthreads();
        if (tid < 128) {
            float acc = bq0[tid];
            for (int i = 0; i < 128; ++i) acc += srow[i] * Wq0[i * 128 + tid];
            Qh0f[blk * 128 + tid] = acc;
            Qh0b[blk * 128 + tid] = f2b(acc);
        }
    } else {
        const float* src = (blk == 128) ? Wk0 : (blk == 129) ? Wv0 : (blk == 130) ? Wq1 : Wo1;
        unsigned short* dst = (blk == 128) ? WkT : (blk == 129) ? WvT : (blk == 130) ? WqT : WoT;
        for (int e = tid; e < 16384; e += 256) {
            int i = e >> 7, n = e & 127;
            dst[n * 128 + i] = f2b(src[e]);
        }
    }
}

// ---------------- MAB0 flash (MFMA), dynamic key-split ----------------
__global__ __launch_bounds__(512)
void k_flash0(const float* __restrict__ Z, const unsigned short* __restrict__ Qh0b,
              const unsigned short* __restrict__ WkT, const unsigned short* __restrict__ WvT,
              const float* __restrict__ bk0, const float* __restrict__ bv0,
              const int* __restrict__ nvalid, float* __restrict__ ml,
              unsigned short* __restrict__ accp)
{
    const int chunk = blockIdx.x, b = blockIdx.y;
    const int tid = threadIdx.x, lane = tid & 63, w = tid >> 6;
    const int l16 = lane & 15, g4 = lane >> 4;
    const f32x4 fz = {0.f, 0.f, 0.f, 0.f};

    __shared__ unsigned short sZ[32 * 136];   // [kk][i]
    __shared__ unsigned short sKh[32 * 136];  // [kk][d]
    __shared__ unsigned short sVT[128 * 40];  // [d][kk]
    __shared__ float sS[128 * 33];            // [q][kk]
    __shared__ unsigned short sP[128 * 40];   // [q][kk]
    __shared__ float sM[NH * 128], sL[NH * 128], sScale[128];

    for (int e = tid; e < NH * 128; e += 512) { sM[e] = -1e30f; sL[e] = 0.f; }

    f32x4 acc[8];
    for (int n = 0; n < 8; ++n) acc[n] = fz;

    int nv = nvalid[b];
    int c0 = (int)(((long long)chunk * nv) / KS);
    int c1 = (int)(((long long)(chunk + 1) * nv) / KS);

    float bkd = bk0[w * 16 + l16];
    float bvd = bv0[w * 16 + l16];

    __syncthreads();

    for (int kt = c0; kt < c1; kt += 32) {
        int nk = min(32, c1 - kt);
        // stage Z tile f32->bf16
        {
            int r = tid >> 4, c = (tid & 15) * 8;
            bf16x8 v;
            if (r < nk) {
                const float* src = &Z[((size_t)b * LL + kt + r) * LAT + c];
                for (int j = 0; j < 8; ++j) ((unsigned short*)&v)[j] = f2b(src[j]);
            } else {
                for (int j = 0; j < 8; ++j) ((unsigned short*)&v)[j] = 0;
            }
            *(bf16x8*)&sZ[r * 136 + c] = v;
        }
        __syncthreads();
        // KV projection: wave w -> d-cols 16w..16w+15
        {
            f32x4 ck[2] = {fz, fz}, cv[2] = {fz, fz};
            for (int k = 0; k < 4; ++k) {
                bf16x8 a0 = *(const bf16x8*)&sZ[(l16) * 136 + k * 32 + g4 * 8];
                bf16x8 a1 = *(const bf16x8*)&sZ[(16 + l16) * 136 + k * 32 + g4 * 8];
                bf16x8 bk_ = *(const bf16x8*)&WkT[(w * 16 + l16) * 128 + k * 32 + g4 * 8];
                bf16x8 bv_ = *(const bf16x8*)&WvT[(w * 16 + l16) * 128 + k * 32 + g4 * 8];
                ck[0] = MFMA(a0, bk_, ck[0], 0, 0, 0);
                ck[1] = MFMA(a1, bk_, ck[1], 0, 0, 0);
                cv[0] = MFMA(a0, bv_, cv[0], 0, 0, 0);
                cv[1] = MFMA(a1, bv_, cv[1], 0, 0, 0);
            }
            for (int m = 0; m < 2; ++m)
                for (int r = 0; r < 4; ++r) {
                    int kk = m * 16 + g4 * 4 + r;
                    int d = w * 16 + l16;
                    sKh[kk * 136 + d] = f2b(ck[m][r] + bkd);
                    sVT[d * 40 + kk] = f2b(cv[m][r] + bvd);
                }
        }
        __syncthreads();
        for (int h = 0; h < NH; ++h) {
            // scores: wave w owns q-rows 16w..16w+15
            bf16x8 aq = *(const bf16x8*)&Qh0b[(w * 16 + l16) * 128 + h * 32 + g4 * 8];
            for (int n = 0; n < 2; ++n) {
                bf16x8 bk_ = *(const bf16x8*)&sKh[(n * 16 + l16) * 136 + h * 32 + g4 * 8];
                f32x4 s = MFMA(aq, bk_, fz, 0, 0, 0);
                for (int r = 0; r < 4; ++r)
                    sS[(w * 16 + g4 * 4 + r) * 33 + n * 16 + l16] = s[r] * RSQ;
            }
            // wave-local online softmax: 4 lanes per row
            int q = w * 16 + (lane >> 2);
            int k0 = (lane & 3) * 8;
            float sv[8];
            float mx = -1e30f;
            for (int j = 0; j < 8; ++j) {
                int kk = k0 + j;
                sv[j] = (kk < nk) ? sS[q * 33 + kk] : -1e30f;
                mx = fmaxf(mx, sv[j]);
            }
            mx = fmaxf(mx, __shfl_xor(mx, 1));
            mx = fmaxf(mx, __shfl_xor(mx, 2));
            float mr = sM[h * 128 + q];
            float mn = fmaxf(mr, mx);
            float sc = __expf(mr - mn);
            float ls = 0.f;
            bf16x8 pv;
            for (int j = 0; j < 8; ++j) {
                float p = (k0 + j < nk) ? __expf(sv[j] - mn) : 0.f;
                ((unsigned short*)&pv)[j] = f2b(p);
                ls += p;
            }
            *(bf16x8*)&sP[q * 40 + k0] = pv;
            ls += __shfl_xor(ls, 1);
            ls += __shfl_xor(ls, 2);
            if ((lane & 3) == 0) {
                sM[h * 128 + q] = mn;
                sL[h * 128 + q] = sL[h * 128 + q] * sc + ls;
                sScale[q] = sc;
            }
            // rescale this head's acc tiles, then PV
            for (int nn = 0; nn < 2; ++nn) {
                int nt = 2 * h + nn;
                for (int r = 0; r < 4; ++r) {
                    float scq = sScale[w * 16 + g4 * 4 + r];
                    acc[nt][r] *= scq;
                }
            }
            bf16x8 aP = *(const bf16x8*)&sP[(w * 16 + l16) * 40 + g4 * 8];
            for (int nn = 0; nn < 2; ++nn) {
                bf16x8 bV = *(const bf16x8*)&sVT[(h * 32 + nn * 16 + l16) * 40 + g4 * 8];
                acc[2 * h + nn] = MFMA(aP, bV, acc[2 * h + nn], 0, 0, 0);
            }
        }
        __syncthreads();
    }
    __syncthreads();
    size_t mlbase = (((size_t)b * KS + chunk) * NH) * 128 * 2;
    for (int e = tid; e < NH * 128; e += 512) {
        ml[mlbase + e * 2 + 0] = sM[e];
        ml[mlbase + e * 2 + 1] = sL[e];
    }
    size_t abase = (((size_t)b * KS + chunk) * 128) * 128;
    for (int n = 0; n < 8; ++n)
        for (int r = 0; r < 4; ++r) {
            int q = w * 16 + g4 * 4 + r;
            int d = n * 16 + l16;
            accp[abase + (size_t)q * 128 + d] = f2b(acc[n][r]);
        }
}

// ---------------- merge MAB0 partials -> O0 = Qh0 + attn ----------------
__global__ __launch_bounds__(128)
void k_merge0(const float* __restrict__ ml, const unsigned short* __restrict__ accp,
              const float* __restrict__ Qh0f, float* __restrict__ O0)
{
    int q = blockIdx.x, b = blockIdx.y, d = threadIdx.x, h = d >> 5;
    float M = -1e30f;
    for (int c = 0; c < KS; ++c)
        M = fmaxf(M, ml[((((size_t)b * KS + c) * NH + h) * 128 + q) * 2]);
    float L = 0.f, A = 0.f;
    for (int c = 0; c < KS; ++c) {
        size_t base = ((((size_t)b * KS + c) * NH + h) * 128 + q) * 2;
        float sc = __expf(ml[base] - M);
        L += sc * ml[base + 1];
        A += sc * b2f(accp[(((size_t)b * KS + c) * 128 + q) * 128 + d]);
    }
    float attn = (L > 0.f) ? A / L : 0.f;
    O0[((size_t)b * 128 + q) * 128 + d] = Qh0f[q * 128 + d] + attn;
}

// ---------------- H = O0 + relu(O0 @ Wo0 + bo0) ----------------
__global__ __launch_bounds__(128)
void k_mlp_res(const float* __restrict__ X, const float* __restrict__ W,
               const float* __restrict__ bias, float* __restrict__ Y)
{
    int row = blockIdx.y * gridDim.x + blockIdx.x;
    int k = threadIdx.x;
    __shared__ float sx[128];
    sx[k] = X[(size_t)row * 128 + k];
    __syncthreads();
    float acc = bias[k];
    for (int i = 0; i < 128; ++i) acc += sx[i] * W[i * 128 + k];
    Y[(size_t)row * 128 + k] = sx[k] + fmaxf(acc, 0.f);
}

// ---------------- Kh1b (bf16 [kk][d]) / Vh1Tb (bf16 [d][kk]) ----------------
__global__ __launch_bounds__(128)
void k_kv1(const float* __restrict__ H, const float* __restrict__ Wk,
           const float* __restrict__ bk, const float* __restrict__ Wv,
           const float* __restrict__ bv,
           unsigned short* __restrict__ Kh1b, unsigned short* __restrict__ Vh1Tb)
{
    int kk = blockIdx.x, b = blockIdx.y;
    int k = threadIdx.x;
    __shared__ float sx[128];
    sx[k] = H[((size_t)b * 128 + kk) * 128 + k];
    __syncthreads();
    float ak = bk[k], av = bv[k];
    for (int i = 0; i < 128; ++i) {
        float x = sx[i];
        ak += x * Wk[i * 128 + k];
        av += x * Wv[i * 128 + k];
    }
    Kh1b[((size_t)b * 128 + kk) * 128 + k] = f2b(ak);
    Vh1Tb[((size_t)b * 128 + k) * 128 + kk] = f2b(av);
}

// ---------------- MAB1 fused (MFMA), 64 rows/block ----------------
__global__ __launch_bounds__(512)
void k_mab1(float* __restrict__ Z, const unsigned short* __restrict__ Kh1b,
            const unsigned short* __restrict__ Vh1Tb,
            const unsigned short* __restrict__ WqT, const float* __restrict__ bq1,
            const unsigned short* __restrict__ WoT, const float* __restrict__ bo1,
            const int* __restrict__ nvalid)
{
    const int b = blockIdx.y;
    const int p0 = blockIdx.x * 64;
    const int nv = nvalid[b];
    if (p0 >= nv) return;
    const int nr = min(64, nv - p0);
    const int tid = threadIdx.x, lane = tid & 63, w = tid >> 6;
    const int l16 = lane & 15, g4 = lane >> 4;
    const f32x4 fz = {0.f, 0.f, 0.f, 0.f};

    __shared__ unsigned short sZ[64 * 136];
    __shared__ unsigned short sQh[64 * 136];
    __shared__ float sS[64 * 129];
    __shared__ unsigned short sP[64 * 136];
    __shared__ unsigned short sO[64 * 136];
    __shared__ float sInv[64];

    {
        int r = tid >> 3, c = (tid & 7) * 16;
        for (int half = 0; half < 2; ++half) {
            bf16x8 v;
            if (r < nr) {
                const float* src = &Z[((size_t)b * LL + p0 + r) * LAT + c + half * 8];
                for (int j = 0; j < 8; ++j) ((unsigned short*)&v)[j] = f2b(src[j]);
            } else {
                for (int j = 0; j < 8; ++j) ((unsigned short*)&v)[j] = 0;
            }
            *(bf16x8*)&sZ[r * 136 + c + half * 8] = v;
        }
    }
    __syncthreads();
    // Qh1 = Z @ Wq1 + bq1 : wave w -> out-col tile w
    {
        f32x4 c4[4];
        for (int m = 0; m < 4; ++m) c4[m] = fz;
        for (int k = 0; k < 4; ++k) {
            bf16x8 bw = *(const bf16x8*)&WqT[(w * 16 + l16) * 128 + k * 32 + g4 * 8];
            for (int m = 0; m < 4; ++m) {
                bf16x8 a = *(const bf16x8*)&sZ[(m * 16 + l16) * 136 + k * 32 + g4 * 8];
                c4[m] = MFMA(a, bw, c4[m], 0, 0, 0);
            }
        }
        float bqv = bq1[w * 16 + l16];
        for (int m = 0; m < 4; ++m)
            for (int r = 0; r < 4; ++r)
                sQh[(m * 16 + g4 * 4 + r) * 136 + w * 16 + l16] = f2b(c4[m][r] + bqv);
    }
    __syncthreads();
    for (int h = 0; h < NH; ++h) {
        // scores: wave w -> kk tile w
        {
            bf16x8 bk_ = *(const bf16x8*)&Kh1b[((size_t)b * 128 + w * 16 + l16) * 128 + h * 32 + g4 * 8];
            for (int m = 0; m < 4; ++m) {
                bf16x8 aq = *(const bf16x8*)&sQh[(m * 16 + l16) * 136 + h * 32 + g4 * 8];
                f32x4 s = MFMA(aq, bk_, fz, 0, 0, 0);
                for (int r = 0; r < 4; ++r)
                    sS[(m * 16 + g4 * 4 + r) * 129 + w * 16 + l16] = s[r] * RSQ;
            }
        }
        __syncthreads();
        // softmax: wave w -> rows 8w..8w+7, 8 lanes/row
        {
            int row = 8 * w + (lane >> 3);
            int c0 = (lane & 7) * 16;
            float mx = -1e30f;
            for (int j = 0; j < 16; ++j) mx = fmaxf(mx, sS[row * 129 + c0 + j]);
            mx = fmaxf(mx, __shfl_xor(mx, 1));
            mx = fmaxf(mx, __shfl_xor(mx, 2));
            mx = fmaxf(mx, __shfl_xor(mx, 4));
            float ls = 0.f;
            for (int half = 0; half < 2; ++half) {
                bf16x8 pv;
                for (int j = 0; j < 8; ++j) {
                    float p = __expf(sS[row * 129 + c0 + half * 8 + j] - mx);
                    ((unsigned short*)&pv)[j] = f2b(p);
                    ls += p;
                }
                *(bf16x8*)&sP[row * 136 + c0 + half * 8] = pv;
            }
            ls += __shfl_xor(ls, 1);
            ls += __shfl_xor(ls, 2);
            ls += __shfl_xor(ls, 4);
            if ((lane & 7) == 0) sInv[row] = 1.f / ls;
        }
        __syncthreads();
        // PV: wave w -> (m = w&3, n = w>>2)
        {
            int m = w & 3, n = w >> 2;
            f32x4 o = fz;
            for (int k = 0; k < 4; ++k) {
                bf16x8 aP = *(const bf16x8*)&sP[(m * 16 + l16) * 136 + k * 32 + g4 * 8];
                bf16x8 bV = *(const bf16x8*)&Vh1Tb[((size_t)b * 128 + h * 32 + n * 16 + l16) * 128 + k * 32 + g4 * 8];
                o = MFMA(aP, bV, o, 0, 0, 0);
            }
            for (int r = 0; r < 4; ++r) {
                int row = m * 16 + g4 * 4 + r;
                int col = h * 32 + n * 16 + l16;
                float val = o[r] * sInv[row] + b2f(sQh[row * 136 + col]);
                sO[row * 136 + col] = f2b(val);
            }
        }
    }
    __syncthreads();
    // out = Zold + O + relu(O @ Wo1 + bo1) : wave w -> out-col tile w
    {
        f32x4 c4[4];
        for (int m = 0; m < 4; ++m) c4[m] = fz;
        for (int k = 0; k < 4; ++k) {
            bf16x8 bw = *(const bf16x8*)&WoT[(w * 16 + l16) * 128 + k * 32 + g4 * 8];
            for (int m = 0; m < 4; ++m) {
                bf16x8 a = *(const bf16x8*)&sO[(m * 16 + l16) * 136 + k * 32 + g4 * 8];
                c4[m] = MFMA(a, bw, c4[m], 0, 0, 0);
            }
        }
        float bov = bo1[w * 16 + l16];
        for (int m = 0; m < 4; ++m)
            for (int r = 0; r < 4; ++r) {
                int row = m * 16 + g4 * 4 + r;
                int col = w * 16 + l16;
                if (p0 + row < nv) {
                    size_t zi = ((size_t)b * LL + p0 + row) * LAT + col;
                    float Ov = b2f(sO[row * 136 + col]);
                    Z[zi] = Z[zi] + Ov + fmaxf(c4[m][r] + bov, 0.f);
                }
            }
    }
}

extern "C" void kernel_launch(void* const* d_in, const int* in_sizes, int n_in,
                              void* d_out, int out_size, void* d_ws, size_t ws_size,
                              hipStream_t stream)
{
    const float* time_x  = (const float*)d_in[0];
    const float* value_x = (const float*)d_in[1];
    const int*   mask_x  = (const int*)d_in[2];
    const float* Wi = (const float*)d_in[3];
    const float* bi = (const float*)d_in[4];
    const float* I  = (const float*)d_in[5];
    const float* Wq = (const float*)d_in[6];
    const float* bq = (const float*)d_in[7];
    const float* Wk = (const float*)d_in[8];
    const float* bk = (const float*)d_in[9];
    const float* Wv = (const float*)d_in[10];
    const float* bv = (const float*)d_in[11];
    const float* Wo = (const float*)d_in[12];
    const float* bo = (const float*)d_in[13];
    float* out = (float*)d_out;

    const size_t BL = (size_t)BB * LL;
    float* ws = (float*)d_ws;
    float* compT  = ws;                      ws += BL;
    float* compU  = ws;                      ws += BL;
    int*   compC  = (int*)ws;                ws += BL;
    int*   nvalid = (int*)ws;                ws += 64;
    float* Qh0f   = ws;                      ws += 16384;
    float* O0     = ws;                      ws += (size_t)BB * 16384;
    float* H      = ws;                      ws += (size_t)BB * 16384;
    float* ml     = ws;                      ws += (size_t)BB * KS * NH * 128 * 2;
    unsigned short* accp  = (unsigned short*)ws;  ws += ((size_t)BB * KS * 128 * 128) / 2;
    unsigned short* Qh0b  = (unsigned short*)ws;  ws += 8192;
    unsigned short* WkT   = (unsigned short*)ws;  ws += 8192;
    unsigned short* WvT   = (unsigned short*)ws;  ws += 8192;
    unsigned short* WqT   = (unsigned short*)ws;  ws += 8192;
    unsigned short* WoT   = (unsigned short*)ws;  ws += 8192;
    unsigned short* Kh1b  = (unsigned short*)ws;  ws += ((size_t)BB * 16384) / 2;
    unsigned short* Vh1Tb = (unsigned short*)ws;  ws += ((size_t)BB * 16384) / 2;

    k_compact<<<BB, 256, 0, stream>>>(time_x, value_x, mask_x, compT, compU, compC, nvalid);
    k_init<<<dim3(LL / 8, BB), 256, 0, stream>>>(Wi, bi, compT, compU, compC, nvalid, out);

    for (int l = 0; l < NL; ++l) {
        const float* Wq0 = Wq + (size_t)(l * 2 + 0) * 16384;
        const float* Wk0 = Wk + (size_t)(l * 2 + 0) * 16384;
        const float* Wv0 = Wv + (size_t)(l * 2 + 0) * 16384;
        const float* Wo0 = Wo + (size_t)(l * 2 + 0) * 16384;
        const float* Wq1 = Wq + (size_t)(l * 2 + 1) * 16384;
        const float* Wk1 = Wk + (size_t)(l * 2 + 1) * 16384;
        const float* Wv1 = Wv + (size_t)(l * 2 + 1) * 16384;
        const float* Wo1 = Wo + (size_t)(l * 2 + 1) * 16384;
        const float* bq0 = bq + (l * 2 + 0) * 128;
        const float* bk0 = bk + (l * 2 + 0) * 128;
        const float* bv0 = bv + (l * 2 + 0) * 128;
        const float* bo0 = bo + (l * 2 + 0) * 128;
        const float* bq1 = bq + (l * 2 + 1) * 128;
        const float* bk1 = bk + (l * 2 + 1) * 128;
        const float* bv1 = bv + (l * 2 + 1) * 128;
        const float* bo1 = bo + (l * 2 + 1) * 128;
        const float* Il  = I + (size_t)l * 16384;

        k_prep<<<132, 256, 0, stream>>>(Il, Wq0, bq0, Wk0, Wv0, Wq1, Wo1,
                                        Qh0f, Qh0b, WkT, WvT, WqT, WoT);
        k_flash0<<<dim3(KS, BB), 512, 0, stream>>>(out, Qh0b, WkT, WvT, bk0, bv0,
                                                   nvalid, ml, accp);
        k_merge0<<<dim3(128, BB), 128, 0, stream>>>(ml, accp, Qh0f, O0);
        k_mlp_res<<<dim3(128, BB), 128, 0, stream>>>(O0, Wo0, bo0, H);
        k_kv1<<<dim3(128, BB), 128, 0, stream>>>(H, Wk1, bk1, Wv1, bv1, Kh1b, Vh1Tb);
        k_mab1<<<dim3(LL / 64, BB), 512, 0, stream>>>(out, Kh1b, Vh1Tb,
                                                      WqT, bq1, WoT, bo1, nvalid);
    }
}